// Round 1
// baseline (141.453 us; speedup 1.0000x reference)
//
#include <hip/hip_runtime.h>
#include <math.h>

#define DCOLS 1024
#define PHI_F 1.61803398874989484820f

__global__ __launch_bounds__(256) void echo_kernel(
    const float* __restrict__ x_real,
    const float* __restrict__ x_imag,
    const float* __restrict__ t,
    const float* __restrict__ trig_r,
    const float* __restrict__ trig_i,
    const float* __restrict__ w_query,
    const float* __restrict__ b_query,
    const float* __restrict__ w_out,
    const float* __restrict__ b_out,
    const float* __restrict__ beta,
    float* __restrict__ out_real,
    float* __restrict__ out_imag)
{
    const int b   = blockIdx.x;
    const int tid = threadIdx.x;
    const int d0  = tid << 2;                  // 4 columns per thread
    const long base = (long)b * DCOLS + d0;

    const float tphi2 = 2.0f * PHI_F * t[b];

    // ---- load this thread's 4 columns (row data read ONCE, kept in regs) ----
    float4 xr = *reinterpret_cast<const float4*>(x_real + base);
    float4 xi = *reinterpret_cast<const float4*>(x_imag + base);
    float4 wq = *reinterpret_cast<const float4*>(w_query + d0);
    float4 bq = *reinterpret_cast<const float4*>(b_query + d0);
    float4 tr = *reinterpret_cast<const float4*>(trig_r  + d0);
    float4 ti = *reinterpret_cast<const float4*>(trig_i  + d0);

    // ---- phase 1: per-thread partial of the per-row reduction ----
    // th_r + th_i = (xr+xi)/(1+|w_q|) + 2*b_q + 2*t*phi
    // q_r = cos(th_r+th_i), q_i = sin(th_r+th_i)   (exact trig identities of the ref)
    float s_sum[4];
    float tot_r = 0.f, tot_i = 0.f;
    #pragma unroll
    for (int k = 0; k < 4; ++k) {
        const float xrk = (&xr.x)[k], xik = (&xi.x)[k];
        const float s = xrk + xik;
        s_sum[k] = s;
        const float inv_wlq = __builtin_amdgcn_rcpf(1.0f + fabsf((&wq.x)[k]));
        const float ang = fmaf(s, inv_wlq, 2.0f * (&bq.x)[k] + tphi2);
        float sn, cs;
        __sincosf(ang, &sn, &cs);
        const float trk = (&tr.x)[k], tik = (&ti.x)[k];
        tot_r = fmaf(cs, trk, fmaf(sn, tik, tot_r));
        tot_i = fmaf(cs, tik, fmaf(-sn, trk, tot_i));
    }

    // ---- block reduction: butterfly within each wave64, then 4 slots in LDS ----
    #pragma unroll
    for (int m = 32; m >= 1; m >>= 1) {
        tot_r += __shfl_xor(tot_r, m, 64);
        tot_i += __shfl_xor(tot_i, m, 64);
    }
    __shared__ float red_r[4], red_i[4];
    const int wid = tid >> 6;
    if ((tid & 63) == 0) { red_r[wid] = tot_r; red_i[wid] = tot_i; }
    __syncthreads();
    float TR = ((red_r[0] + red_r[1]) + (red_r[2] + red_r[3])) * 0.25f;
    float TI = ((red_i[0] + red_i[1]) + (red_i[2] + red_i[3])) * 0.25f;
    const float mag = sqrtf(fmaf(TR, TR, fmaf(TI, TI, 1e-8f)));

    // ---- phase 2: elementwise output ----
    // to_r + to_i = (xr+xi)*mag*write_scale/(1+|w_out|) + 2*b_out + 2*t*phi
    float4 wo = *reinterpret_cast<const float4*>(w_out + d0);
    float4 bo = *reinterpret_cast<const float4*>(b_out + d0);
    float4 be = *reinterpret_cast<const float4*>(beta  + d0);

    float4 o_r, o_i;
    #pragma unroll
    for (int k = 0; k < 4; ++k) {
        const float weff = __builtin_amdgcn_rcpf(1.0f + fabsf((&wo.x)[k]));
        const float beff = __builtin_amdgcn_rcpf(1.0f + fabsf((&be.x)[k]));
        const float decay = fminf(__expf(-beff * weff), 0.9999f);
        const float wscale = weff * (1.0f - decay);
        const float ang = fmaf(s_sum[k], mag * wscale * weff,
                               2.0f * (&bo.x)[k] + tphi2);
        float sn, cs;
        __sincosf(ang, &sn, &cs);
        (&o_r.x)[k] = cs;
        (&o_i.x)[k] = sn;
    }
    *reinterpret_cast<float4*>(out_real + base) = o_r;
    *reinterpret_cast<float4*>(out_imag + base) = o_i;
}

extern "C" void kernel_launch(void* const* d_in, const int* in_sizes, int n_in,
                              void* d_out, int out_size, void* d_ws, size_t ws_size,
                              hipStream_t stream) {
    const float* x_real = (const float*)d_in[0];
    const float* x_imag = (const float*)d_in[1];
    const float* t      = (const float*)d_in[2];
    const float* trig_r = (const float*)d_in[3];
    const float* trig_i = (const float*)d_in[4];
    const float* w_q    = (const float*)d_in[5];
    const float* b_q    = (const float*)d_in[6];
    const float* w_out  = (const float*)d_in[7];
    const float* b_out  = (const float*)d_in[8];
    const float* beta   = (const float*)d_in[9];

    const int B = in_sizes[2];              // 8192 rows (t has one entry per row)
    float* out_real = (float*)d_out;
    float* out_imag = (float*)d_out + (long)B * DCOLS;

    echo_kernel<<<B, 256, 0, stream>>>(x_real, x_imag, t,
                                       trig_r, trig_i, w_q, b_q,
                                       w_out, b_out, beta,
                                       out_real, out_imag);
}

// Round 3
// 129.898 us; speedup vs baseline: 1.0890x; 1.0890x over previous
//
#include <hip/hip_runtime.h>
#include <math.h>

#define DCOLS 1024
#define PHI_F 1.61803398874989484820f

// One wave (64 lanes) per row; each lane owns 16 columns: col = k*256 + lane*4.
// All per-column coefficients hoisted into registers once per wave, reused
// across ROWS_PER_WAVE rows. No LDS, no barriers — reduction is pure shfl_xor.
__global__ __launch_bounds__(256, 2) void echo_kernel(
    const float* __restrict__ x_real, const float* __restrict__ x_imag,
    const float* __restrict__ t,
    const float* __restrict__ trig_r, const float* __restrict__ trig_i,
    const float* __restrict__ w_query, const float* __restrict__ b_query,
    const float* __restrict__ w_out, const float* __restrict__ b_out,
    const float* __restrict__ beta,
    float* __restrict__ out_real, float* __restrict__ out_imag,
    int B, int total_waves)
{
    const int tid  = threadIdx.x;
    const int lane = tid & 63;
    const int wid  = tid >> 6;
    const int wave = (blockIdx.x << 2) + wid;
    const int c0   = lane << 2;               // float4-aligned col within each 256-chunk

    // ---- hoist per-column coefficients (once per wave, reused for all rows) ----
    float invq[16], addq[16], trr[16], tri[16], c2[16], addo[16];
    #pragma unroll
    for (int k = 0; k < 4; ++k) {
        const int c = (k << 8) + c0;
        const float4 wq = *reinterpret_cast<const float4*>(w_query + c);
        const float4 bq = *reinterpret_cast<const float4*>(b_query + c);
        const float4 tr = *reinterpret_cast<const float4*>(trig_r  + c);
        const float4 ti = *reinterpret_cast<const float4*>(trig_i  + c);
        const float4 wo = *reinterpret_cast<const float4*>(w_out   + c);
        const float4 bo = *reinterpret_cast<const float4*>(b_out   + c);
        const float4 be = *reinterpret_cast<const float4*>(beta    + c);
        #pragma unroll
        for (int j = 0; j < 4; ++j) {
            const int e = (k << 2) + j;
            invq[e] = __builtin_amdgcn_rcpf(1.0f + fabsf((&wq.x)[j]));
            addq[e] = 2.0f * (&bq.x)[j];
            trr[e]  = (&tr.x)[j];
            tri[e]  = (&ti.x)[j];
            const float weff  = __builtin_amdgcn_rcpf(1.0f + fabsf((&wo.x)[j]));
            const float beff  = __builtin_amdgcn_rcpf(1.0f + fabsf((&be.x)[j]));
            const float decay = fminf(__expf(-beff * weff), 0.9999f);
            c2[e]   = weff * weff * (1.0f - decay);   // write_scale * w_eff
            addo[e] = 2.0f * (&bo.x)[j];
        }
    }

    int row = wave;
    if (row >= B) return;
    long base = (long)row * DCOLS + c0;

    // ---- preload first row ----
    float4 xr[4], xi[4];
    #pragma unroll
    for (int k = 0; k < 4; ++k) {
        xr[k] = *reinterpret_cast<const float4*>(x_real + base + (k << 8));
        xi[k] = *reinterpret_cast<const float4*>(x_imag + base + (k << 8));
    }
    float tcur = t[row];

    while (true) {
        const int  nrow = row + total_waves;
        const bool more = (nrow < B);
        const float tphi2 = 2.0f * PHI_F * tcur;

        // ---- phase 1: angle + sincos + weighted partial sums ----
        float s[16];
        float tot_r = 0.f, tot_i = 0.f;
        #pragma unroll
        for (int k = 0; k < 4; ++k) {
            #pragma unroll
            for (int j = 0; j < 4; ++j) {
                const int e = (k << 2) + j;
                const float sv = (&xr[k].x)[j] + (&xi[k].x)[j];
                s[e] = sv;
                const float ang = fmaf(sv, invq[e], addq[e] + tphi2);
                float sn, cs;
                __sincosf(ang, &sn, &cs);
                tot_r = fmaf(cs, trr[e], fmaf(sn, tri[e], tot_r));
                tot_i = fmaf(cs, tri[e], fmaf(-sn, trr[e], tot_i));
            }
        }

        // ---- prefetch next row while the shuffle-reduce chain runs ----
        float4 nxr[4], nxi[4];
        float tnext = 0.f;
        const long nbase = (long)nrow * DCOLS + c0;
        if (more) {
            #pragma unroll
            for (int k = 0; k < 4; ++k) {
                nxr[k] = *reinterpret_cast<const float4*>(x_real + nbase + (k << 8));
                nxi[k] = *reinterpret_cast<const float4*>(x_imag + nbase + (k << 8));
            }
            tnext = t[nrow];
        }

        // ---- in-wave reduction (no LDS, no barrier) ----
        #pragma unroll
        for (int m = 32; m >= 1; m >>= 1) {
            tot_r += __shfl_xor(tot_r, m, 64);
            tot_i += __shfl_xor(tot_i, m, 64);
        }
        const float TR = tot_r * 0.25f, TI = tot_i * 0.25f;
        const float mag = sqrtf(fmaf(TR, TR, fmaf(TI, TI, 1e-8f)));

        // ---- phase 2: elementwise outputs ----
        #pragma unroll
        for (int k = 0; k < 4; ++k) {
            float4 o_r, o_i;
            #pragma unroll
            for (int j = 0; j < 4; ++j) {
                const int e = (k << 2) + j;
                const float ang = fmaf(s[e], mag * c2[e], addo[e] + tphi2);
                float sn, cs;
                __sincosf(ang, &sn, &cs);
                (&o_r.x)[j] = cs;
                (&o_i.x)[j] = sn;
            }
            *reinterpret_cast<float4*>(out_real + base + (k << 8)) = o_r;
            *reinterpret_cast<float4*>(out_imag + base + (k << 8)) = o_i;
        }

        if (!more) break;
        row = nrow; base = nbase; tcur = tnext;
        #pragma unroll
        for (int k = 0; k < 4; ++k) { xr[k] = nxr[k]; xi[k] = nxi[k]; }
    }
}

extern "C" void kernel_launch(void* const* d_in, const int* in_sizes, int n_in,
                              void* d_out, int out_size, void* d_ws, size_t ws_size,
                              hipStream_t stream) {
    const float* x_real = (const float*)d_in[0];
    const float* x_imag = (const float*)d_in[1];
    const float* t      = (const float*)d_in[2];
    const float* trig_r = (const float*)d_in[3];
    const float* trig_i = (const float*)d_in[4];
    const float* w_q    = (const float*)d_in[5];
    const float* b_q    = (const float*)d_in[6];
    const float* w_out  = (const float*)d_in[7];
    const float* b_out  = (const float*)d_in[8];
    const float* beta   = (const float*)d_in[9];

    const int B = in_sizes[2];                 // rows (t is per-row)
    float* out_real = (float*)d_out;
    float* out_imag = (float*)d_out + (long)B * DCOLS;

    // 4 rows per wave: blocks = B/16 (4 waves/block)
    const int blocks = (B + 15) / 16;
    const int total_waves = blocks * 4;

    echo_kernel<<<blocks, 256, 0, stream>>>(x_real, x_imag, t,
                                            trig_r, trig_i, w_q, b_q,
                                            w_out, b_out, beta,
                                            out_real, out_imag,
                                            B, total_waves);
}